// Round 1
// baseline (3212.133 us; speedup 1.0000x reference)
//
#include <hip/hip_runtime.h>
#include <stdint.h>

typedef __attribute__((ext_vector_type(8))) short short8;
typedef __attribute__((ext_vector_type(4))) float f32x4;

#define T_   16
#define N_   2048
#define E_   16384
#define NT   32768      // T*N
#define EALL 262144     // T*E
#define EL_  8192

static __device__ __forceinline__ short f2bf(float f){
  union { float f; uint32_t u; } v; v.f = f;
  uint32_t r = (v.u + 0x7FFFu + ((v.u >> 16) & 1u)) >> 16;
  return (short)r;
}
static __device__ __forceinline__ float lrelu(float x){ return x > 0.f ? x : 0.2f*x; }

// ---------------- MFMA GEMM: C[M,N] = act(A[M,K]) @ B[N,K]^T (+bias)(+relu) -------------
// Block = 256 threads = 4 waves in 2x2. Wave tile = (TM*16) x (TN*16).
// A,B fp32 row-major, converted to bf16 on load. m90-verified fragment layout:
//   A-frag: lane holds A[m0 + (l&15)][k0 + (l>>4)*8 + j]; B-frag same from B[N,K].
//   C/D:    lane,reg -> row = (l>>4)*4 + reg, col = l&15.
template<int TM,int TN,bool PREACT,bool EBIAS,bool ERELU,bool OBF16>
__global__ __launch_bounds__(256) void gemm_bt(
    const float* __restrict__ A, const float* __restrict__ ab,
    const float* __restrict__ B, const float* __restrict__ bias,
    float* __restrict__ Cf, short* __restrict__ Cb, int K, int N)
{
  const int lane = threadIdx.x & 63;
  const int wv   = threadIdx.x >> 6;
  const int wi = wv >> 1, wj = wv & 1;
  const int q = lane >> 4, r = lane & 15;
  const int m0 = blockIdx.y * (2*TM*16) + wi * (TM*16);
  const int n0 = blockIdx.x * (2*TN*16) + wj * (TN*16);

  f32x4 acc[TM][TN];
#pragma unroll
  for(int i=0;i<TM;i++)
#pragma unroll
    for(int j=0;j<TN;j++) acc[i][j] = (f32x4){0.f,0.f,0.f,0.f};

  for(int k0=0;k0<K;k0+=32){
    const int ka = k0 + q*8;
    short8 af[TM], bfr[TN];
#pragma unroll
    for(int i=0;i<TM;i++){
      const float* p = A + (size_t)(m0 + i*16 + r)*K + ka;
      float4 u0 = *(const float4*)p;
      float4 u1 = *(const float4*)(p+4);
      float vv[8] = {u0.x,u0.y,u0.z,u0.w,u1.x,u1.y,u1.z,u1.w};
      if (PREACT){
        const float* bb = ab + ka;
        float4 b0 = *(const float4*)bb;
        float4 b1 = *(const float4*)(bb+4);
        float bv[8] = {b0.x,b0.y,b0.z,b0.w,b1.x,b1.y,b1.z,b1.w};
#pragma unroll
        for(int u=0;u<8;u++) vv[u] = fmaxf(vv[u]+bv[u], 0.f);
      }
      short8 s;
#pragma unroll
      for(int u=0;u<8;u++) s[u] = f2bf(vv[u]);
      af[i] = s;
    }
#pragma unroll
    for(int j=0;j<TN;j++){
      const float* p = B + (size_t)(n0 + j*16 + r)*K + ka;
      float4 u0 = *(const float4*)p;
      float4 u1 = *(const float4*)(p+4);
      float vv[8] = {u0.x,u0.y,u0.z,u0.w,u1.x,u1.y,u1.z,u1.w};
      short8 s;
#pragma unroll
      for(int u=0;u<8;u++) s[u] = f2bf(vv[u]);
      bfr[j] = s;
    }
#pragma unroll
    for(int i=0;i<TM;i++)
#pragma unroll
      for(int j=0;j<TN;j++)
        acc[i][j] = __builtin_amdgcn_mfma_f32_16x16x32_bf16(af[i], bfr[j], acc[i][j], 0,0,0);
  }

#pragma unroll
  for(int i=0;i<TM;i++){
#pragma unroll
    for(int j=0;j<TN;j++){
#pragma unroll
      for(int rr=0;rr<4;rr++){
        int row = m0 + i*16 + q*4 + rr;
        int col = n0 + j*16 + r;
        float v = acc[i][j][rr];
        if(EBIAS) v += bias[col];
        if(ERELU) v = fmaxf(v, 0.f);
        if(OBF16) Cb[(size_t)row*N + col] = f2bf(v);
        else      Cf[(size_t)row*N + col] = v;
      }
    }
  }
}

// ---------------- Hop final GEMM: out[t] = h2bf[t] @ fcsum^T + fcb ; 128x128 tiles ------
__global__ __launch_bounds__(256) void hop_gemm(
    const short* __restrict__ Abf, const short* __restrict__ Bbf,
    const float* __restrict__ bias, float* __restrict__ out)
{
  const int lane = threadIdx.x & 63;
  const int wv   = threadIdx.x >> 6;
  const int wi = wv >> 1, wj = wv & 1;
  const int q = lane >> 4, r = lane & 15;
  const int t  = blockIdx.z;
  const int m0 = blockIdx.y * 128 + wi * 64;
  const int n0 = blockIdx.x * 128 + wj * 64;
  const short* Ab = Abf + (size_t)t * N_ * 128;

  f32x4 acc[4][4];
#pragma unroll
  for(int i=0;i<4;i++)
#pragma unroll
    for(int j=0;j<4;j++) acc[i][j] = (f32x4){0.f,0.f,0.f,0.f};

#pragma unroll
  for(int k0=0;k0<128;k0+=32){
    const int ka = k0 + q*8;
    short8 af[4], bfr[4];
#pragma unroll
    for(int i=0;i<4;i++) af[i]  = *(const short8*)(Ab  + (size_t)(m0 + i*16 + r)*128 + ka);
#pragma unroll
    for(int j=0;j<4;j++) bfr[j] = *(const short8*)(Bbf + (size_t)(n0 + j*16 + r)*128 + ka);
#pragma unroll
    for(int i=0;i<4;i++)
#pragma unroll
      for(int j=0;j<4;j++)
        acc[i][j] = __builtin_amdgcn_mfma_f32_16x16x32_bf16(af[i], bfr[j], acc[i][j], 0,0,0);
  }

#pragma unroll
  for(int i=0;i<4;i++){
#pragma unroll
    for(int j=0;j<4;j++){
#pragma unroll
      for(int rr=0;rr<4;rr++){
        int row = m0 + i*16 + q*4 + rr;
        int col = n0 + j*16 + r;
        out[((size_t)t*N_ + row)*N_ + col] = acc[i][j][rr] + bias[col];
      }
    }
  }
}

// ---------------- GAT layer 1 (H=4, C=128) ----------------------------------------------
__global__ void k_asad1(const float* __restrict__ xw1, const float* __restrict__ atts,
                        const float* __restrict__ attd, float* __restrict__ as1,
                        float* __restrict__ ad1){
  int id = blockIdx.x*256 + threadIdx.x;
  if(id >= NT*4) return;
  int n = id >> 2, h = id & 3;
  const float* row = xw1 + (size_t)n*512 + h*128;
  const float* sa = atts + h*128;
  const float* da = attd + h*128;
  float s = 0.f, d = 0.f;
  for(int c=0;c<128;c+=4){
    float4 v = *(const float4*)(row+c);
    float4 a = *(const float4*)(sa+c);
    float4 b = *(const float4*)(da+c);
    s += v.x*a.x + v.y*a.y + v.z*a.z + v.w*a.w;
    d += v.x*b.x + v.y*b.y + v.z*b.z + v.w*b.w;
  }
  as1[id] = s; ad1[id] = d;
}

__global__ void k_self1(const float* __restrict__ as1, const float* __restrict__ ad1,
                        float* __restrict__ den1){
  int id = blockIdx.x*256 + threadIdx.x;
  if(id >= NT*4) return;
  den1[id] = expf(lrelu(as1[id] + ad1[id]));   // self-loop contribution initializes denom
}

__global__ void k_den1e(const int* __restrict__ ei, const float* __restrict__ as1,
                        const float* __restrict__ ad1, float* __restrict__ den1,
                        float* __restrict__ p1){
  int id = blockIdx.x*256 + threadIdx.x;
  if(id >= EALL) return;
  int t = id >> 14, e = id & (E_-1);
  int s = ei[t*2*E_ + e], d = ei[t*2*E_ + E_ + e];
#pragma unroll
  for(int h=0;h<4;h++){
    float p = expf(lrelu(as1[s*4+h] + ad1[d*4+h]));
    p1[id*4+h] = p;
    unsafeAtomicAdd(&den1[d*4+h], p);
  }
}

__global__ void k_z1init(const float* __restrict__ xw1, const float* __restrict__ as1,
                         const float* __restrict__ ad1, const float* __restrict__ den1,
                         float* __restrict__ z1){
  int id = blockIdx.x*256 + threadIdx.x;     // NT * 128 float4 chunks
  if(id >= NT*128) return;
  int n = id >> 7, c4 = id & 127;
  int h = c4 >> 5, nh = n*4 + h;
  float alpha = expf(lrelu(as1[nh] + ad1[nh])) / (den1[nh] + 1e-16f);
  float4 v = *(const float4*)(xw1 + (size_t)n*512 + c4*4);
  float4 o; o.x = v.x*alpha; o.y = v.y*alpha; o.z = v.z*alpha; o.w = v.w*alpha;
  *(float4*)(z1 + (size_t)n*512 + c4*4) = o;
}

__global__ void k_z1e(const int* __restrict__ ei, const float* __restrict__ p1,
                      const float* __restrict__ den1, const float* __restrict__ xw1,
                      float* __restrict__ z1){
  int id = blockIdx.x*256 + threadIdx.x;     // EALL * 128 float4 chunks
  if(id >= EALL*128) return;
  int eidx = id >> 7, c4 = id & 127;
  int t = eidx >> 14, e = eidx & (E_-1);
  int s = ei[t*2*E_ + e], d = ei[t*2*E_ + E_ + e];
  int h = c4 >> 5;
  float w = p1[eidx*4+h] / (den1[d*4+h] + 1e-16f);
  float4 v = *(const float4*)(xw1 + (size_t)s*512 + c4*4);
  float* dst = z1 + (size_t)d*512 + c4*4;
  unsafeAtomicAdd(dst+0, v.x*w);
  unsafeAtomicAdd(dst+1, v.y*w);
  unsafeAtomicAdd(dst+2, v.z*w);
  unsafeAtomicAdd(dst+3, v.w*w);
}

// ---------------- GAT layer 2 (H=1, C=64) -----------------------------------------------
__global__ void k_asad2(const float* __restrict__ xw2, const float* __restrict__ atts,
                        const float* __restrict__ attd, float* __restrict__ as2,
                        float* __restrict__ ad2){
  int n = blockIdx.x*256 + threadIdx.x;
  if(n >= NT) return;
  const float* row = xw2 + (size_t)n*64;
  float s = 0.f, d = 0.f;
  for(int c=0;c<64;c+=4){
    float4 v = *(const float4*)(row+c);
    float4 a = *(const float4*)(atts+c);
    float4 b = *(const float4*)(attd+c);
    s += v.x*a.x + v.y*a.y + v.z*a.z + v.w*a.w;
    d += v.x*b.x + v.y*b.y + v.z*b.z + v.w*b.w;
  }
  as2[n] = s; ad2[n] = d;
}

__global__ void k_self2(const float* __restrict__ as2, const float* __restrict__ ad2,
                        float* __restrict__ den2){
  int n = blockIdx.x*256 + threadIdx.x;
  if(n >= NT) return;
  den2[n] = expf(lrelu(as2[n] + ad2[n]));
}

__global__ void k_den2e(const int* __restrict__ ei, const float* __restrict__ as2,
                        const float* __restrict__ ad2, float* __restrict__ den2,
                        float* __restrict__ p2){
  int id = blockIdx.x*256 + threadIdx.x;
  if(id >= EALL) return;
  int t = id >> 14, e = id & (E_-1);
  int s = ei[t*2*E_ + e], d = ei[t*2*E_ + E_ + e];
  float p = expf(lrelu(as2[s] + ad2[d]));
  p2[id] = p;
  unsafeAtomicAdd(&den2[d], p);
}

__global__ void k_z2init(const float* __restrict__ xw2, const float* __restrict__ as2,
                         const float* __restrict__ ad2, const float* __restrict__ den2,
                         const float* __restrict__ b2, float* __restrict__ z2){
  int id = blockIdx.x*256 + threadIdx.x;     // NT*16 float4 chunks
  if(id >= NT*16) return;
  int n = id >> 4, c4 = id & 15;
  float alpha = expf(lrelu(as2[n] + ad2[n])) / (den2[n] + 1e-16f);
  float4 v = *(const float4*)(xw2 + (size_t)n*64 + c4*4);
  float4 b = *(const float4*)(b2 + c4*4);
  float4 o; o.x = v.x*alpha+b.x; o.y = v.y*alpha+b.y; o.z = v.z*alpha+b.z; o.w = v.w*alpha+b.w;
  *(float4*)(z2 + (size_t)n*64 + c4*4) = o;
}

__global__ void k_z2e(const int* __restrict__ ei, const float* __restrict__ p2,
                      const float* __restrict__ den2, const float* __restrict__ xw2,
                      float* __restrict__ z2){
  int id = blockIdx.x*256 + threadIdx.x;     // EALL*16 float4 chunks
  if(id >= EALL*16) return;
  int eidx = id >> 4, c4 = id & 15;
  int t = eidx >> 14, e = eidx & (E_-1);
  int s = ei[t*2*E_ + e], d = ei[t*2*E_ + E_ + e];
  float w = p2[eidx] / (den2[d] + 1e-16f);
  float4 v = *(const float4*)(xw2 + (size_t)s*64 + c4*4);
  float* dst = z2 + (size_t)d*64 + c4*4;
  unsafeAtomicAdd(dst+0, v.x*w);
  unsafeAtomicAdd(dst+1, v.y*w);
  unsafeAtomicAdd(dst+2, v.z*w);
  unsafeAtomicAdd(dst+3, v.w*w);
}

__global__ void k_linkpred(const float* __restrict__ z2, const int* __restrict__ eli,
                           float* __restrict__ out){
  int pair = blockIdx.x*4 + (threadIdx.x >> 6);
  int lane = threadIdx.x & 63;
  if(pair >= EL_) return;
  int a = eli[pair], b = eli[EL_ + pair];
  float v = z2[(size_t)a*64 + lane] * z2[(size_t)b*64 + lane];
  for(int off=32; off; off >>= 1) v += __shfl_down(v, off);
  if(lane == 0) out[pair] = v;
}

// ---------------- GCN (hop) branch ------------------------------------------------------
__global__ void k_deginit(float* __restrict__ deg){
  int n = blockIdx.x*256 + threadIdx.x;
  if(n < NT) deg[n] = 1.0f;                   // self-loop weight
}
__global__ void k_degadd(const int* __restrict__ ei, const float* __restrict__ ew,
                         float* __restrict__ deg){
  int id = blockIdx.x*256 + threadIdx.x;
  if(id >= EALL) return;
  int t = id >> 14, e = id & (E_-1);
  int d = ei[t*2*E_ + E_ + e];
  unsafeAtomicAdd(&deg[t*N_ + d], ew[id]);
}
__global__ void k_dinv(float* __restrict__ deg){
  int n = blockIdx.x*256 + threadIdx.x;
  if(n < NT) deg[n] = rsqrtf(deg[n]);
}

template<int F>
__global__ void k_gcninit(const float* __restrict__ feats, const float* __restrict__ dinv,
                          float* __restrict__ acc){
  int id = blockIdx.x*256 + threadIdx.x;     // NT * (F/4) chunks
  if(id >= NT*(F/4)) return;
  int n = id / (F/4), c4 = id % (F/4);
  float di = dinv[n];
  float c = di*di;                            // self-loop norm = 1/deg
  float4 v = *(const float4*)(feats + (size_t)n*F + c4*4);
  float4 o; o.x = v.x*c; o.y = v.y*c; o.z = v.z*c; o.w = v.w*c;
  *(float4*)(acc + (size_t)n*F + c4*4) = o;
}

template<int F>
__global__ void k_gcne(const int* __restrict__ ei, const float* __restrict__ ew,
                       const float* __restrict__ dinv, const float* __restrict__ feats,
                       float* __restrict__ acc){
  int id = blockIdx.x*256 + threadIdx.x;     // EALL * (F/4) chunks
  if(id >= EALL*(F/4)) return;
  int eidx = id / (F/4), c4 = id % (F/4);
  int t = eidx >> 14, e = eidx & (E_-1);
  int s = ei[t*2*E_ + e], d = ei[t*2*E_ + E_ + e];
  int gs = t*N_ + s, gd = t*N_ + d;
  float coeff = dinv[gs] * ew[eidx] * dinv[gd];
  float4 v = *(const float4*)(feats + (size_t)gs*F + c4*4);
  float* dst = acc + (size_t)gd*F + c4*4;
  unsafeAtomicAdd(dst+0, v.x*coeff);
  unsafeAtomicAdd(dst+1, v.y*coeff);
  unsafeAtomicAdd(dst+2, v.z*coeff);
  unsafeAtomicAdd(dst+3, v.w*coeff);
}

__global__ void k_fcsum(const float* __restrict__ fcw, short* __restrict__ wbf){
  int id = blockIdx.x*256 + threadIdx.x;     // 2048*128
  if(id >= N_*128) return;
  int j = id >> 7, k = id & 127;
  wbf[id] = f2bf(fcw[j*256 + k] + fcw[j*256 + 128 + k]);
}

// ---------------- launcher --------------------------------------------------------------
extern "C" void kernel_launch(void* const* d_in, const int* in_sizes, int n_in,
                              void* d_out, int out_size, void* d_ws, size_t ws_size,
                              hipStream_t stream) {
  const float* x       = (const float*)d_in[0];
  const int*   ei      = (const int*)d_in[1];
  const float* eattr   = (const float*)d_in[2];
  const int*   eli     = (const int*)d_in[3];
  const float* conv1_w = (const float*)d_in[4];
  const float* conv1_b = (const float*)d_in[5];
  const float* conv2_w = (const float*)d_in[6];
  const float* conv2_b = (const float*)d_in[7];
  const float* gat1_w  = (const float*)d_in[8];
  const float* g1as    = (const float*)d_in[9];
  const float* g1ad    = (const float*)d_in[10];
  const float* gat1_b  = (const float*)d_in[11];
  const float* gat2_w  = (const float*)d_in[12];
  const float* g2as    = (const float*)d_in[13];
  const float* g2ad    = (const float*)d_in[14];
  const float* gat2_b  = (const float*)d_in[15];
  const float* fcw     = (const float*)d_in[16];
  const float* fcb     = (const float*)d_in[17];

  // workspace carve
  char* wp = (char*)d_ws;
  auto alloc = [&](size_t bytes)->void*{ void* r = wp; wp += (bytes + 255) & ~(size_t)255; return r; };
  float* as1   = (float*)alloc((size_t)NT*4*4);
  float* ad1   = (float*)alloc((size_t)NT*4*4);
  float* den1  = (float*)alloc((size_t)NT*4*4);
  float* p1    = (float*)alloc((size_t)EALL*4*4);
  float* xw2   = (float*)alloc((size_t)NT*64*4);
  float* as2   = (float*)alloc((size_t)NT*4);
  float* ad2   = (float*)alloc((size_t)NT*4);
  float* den2  = (float*)alloc((size_t)NT*4);
  float* p2    = (float*)alloc((size_t)EALL*4);
  float* z2    = (float*)alloc((size_t)NT*64*4);
  float* dinv  = (float*)alloc((size_t)NT*4);
  float* accx  = (float*)alloc((size_t)NT*64*4);
  float* h1    = (float*)alloc((size_t)NT*128*4);
  float* acch  = (float*)alloc((size_t)NT*128*4);
  short* h2bf  = (short*)alloc((size_t)NT*128*2);
  short* fcsbf = (short*)alloc((size_t)N_*128*2);

  // d_out layout: [0:8192) link_pred, [8192:...) hop_out (16*2048*2048).
  // The hop region doubles as scratch for the two 64MB GAT buffers (consumed
  // before hop_gemm overwrites the region).
  float* outf     = (float*)d_out;
  float* link_out = outf;
  float* hop_out  = outf + EL_;
  float* xw1      = hop_out;                       // 16,777,216 floats
  float* z1       = hop_out + (size_t)NT*512;      // 16,777,216 floats

  dim3 blk(256);

  // ---- GAT branch ----
  // xw1 = x @ gat1_w^T   [32768,512], K=64
  gemm_bt<4,4,false,false,false,false><<<dim3(4,256), blk, 0, stream>>>(
      x, nullptr, gat1_w, nullptr, xw1, nullptr, 64, 512);
  k_asad1<<<dim3((NT*4)/256), blk, 0, stream>>>(xw1, g1as, g1ad, as1, ad1);
  k_self1<<<dim3((NT*4)/256), blk, 0, stream>>>(as1, ad1, den1);
  k_den1e<<<dim3(EALL/256), blk, 0, stream>>>(ei, as1, ad1, den1, p1);
  k_z1init<<<dim3((NT*128)/256), blk, 0, stream>>>(xw1, as1, ad1, den1, z1);
  k_z1e<<<dim3((EALL*128)/256), blk, 0, stream>>>(ei, p1, den1, xw1, z1);
  // xw2 = relu(z1 + gat1_b) @ gat2_w^T   [32768,64], K=512
  gemm_bt<4,2,true,false,false,false><<<dim3(1,256), blk, 0, stream>>>(
      z1, gat1_b, gat2_w, nullptr, xw2, nullptr, 512, 64);
  k_asad2<<<dim3(NT/256), blk, 0, stream>>>(xw2, g2as, g2ad, as2, ad2);
  k_self2<<<dim3(NT/256), blk, 0, stream>>>(as2, ad2, den2);
  k_den2e<<<dim3(EALL/256), blk, 0, stream>>>(ei, as2, ad2, den2, p2);
  k_z2init<<<dim3((NT*16)/256), blk, 0, stream>>>(xw2, as2, ad2, den2, gat2_b, z2);
  k_z2e<<<dim3((EALL*16)/256), blk, 0, stream>>>(ei, p2, den2, xw2, z2);
  k_linkpred<<<dim3(EL_/4), blk, 0, stream>>>(z2, eli, link_out);

  // ---- hop (GCN) branch ----
  k_deginit<<<dim3(NT/256), blk, 0, stream>>>(dinv);
  k_degadd<<<dim3(EALL/256), blk, 0, stream>>>(ei, eattr, dinv);
  k_dinv<<<dim3(NT/256), blk, 0, stream>>>(dinv);
  // conv1: scatter x then (ÂX) @ W1^T + b1, relu
  k_gcninit<64><<<dim3((NT*16)/256), blk, 0, stream>>>(x, dinv, accx);
  k_gcne<64><<<dim3((EALL*16)/256), blk, 0, stream>>>(ei, eattr, dinv, x, accx);
  gemm_bt<4,4,false,true,true,false><<<dim3(1,256), blk, 0, stream>>>(
      accx, nullptr, conv1_w, conv1_b, h1, nullptr, 64, 128);
  // conv2
  k_gcninit<128><<<dim3((NT*32)/256), blk, 0, stream>>>(h1, dinv, acch);
  k_gcne<128><<<dim3((EALL*32)/256), blk, 0, stream>>>(ei, eattr, dinv, h1, acch);
  gemm_bt<4,4,false,true,true,true><<<dim3(1,256), blk, 0, stream>>>(
      acch, nullptr, conv2_w, conv2_b, nullptr, h2bf, 128, 128);
  // hop_out = h2 @ (fcw[:, :128]+fcw[:,128:])^T + fcb
  k_fcsum<<<dim3((N_*128)/256), blk, 0, stream>>>(fcw, fcsbf);
  hop_gemm<<<dim3(16,16,16), blk, 0, stream>>>(h2bf, fcsbf, fcb, hop_out);
}

// Round 2
// 804.363 us; speedup vs baseline: 3.9934x; 3.9934x over previous
//
#include <hip/hip_runtime.h>
#include <stdint.h>

typedef __attribute__((ext_vector_type(8))) short short8;
typedef __attribute__((ext_vector_type(4))) float f32x4;

#define T_   16
#define N_   2048
#define E_   16384
#define NT   32768      // T*N
#define EALL 262144     // T*E
#define EL_  8192

static __device__ __forceinline__ short f2bf(float f){
  union { float f; uint32_t u; } v; v.f = f;
  uint32_t r = (v.u + 0x7FFFu + ((v.u >> 16) & 1u)) >> 16;
  return (short)r;
}
static __device__ __forceinline__ float lrelu(float x){ return x > 0.f ? x : 0.2f*x; }

// ---------------- CSR build: key = t*2048 + dst -----------------------------------------
__global__ void k_zero(int* __restrict__ p, int n){
  int i = blockIdx.x*256 + threadIdx.x;
  if(i < n) p[i] = 0;
}
__global__ void k_cnt(const int* __restrict__ ei, int* __restrict__ cnt){
  int id = blockIdx.x*256 + threadIdx.x;
  if(id >= EALL) return;
  int t = id >> 14, e = id & (E_-1);
  int d = ei[t*2*E_ + E_ + e];
  atomicAdd(&cnt[t*N_ + d], 1);
}
__global__ __launch_bounds__(1024) void k_scan(const int* __restrict__ cnt, int* __restrict__ off){
  __shared__ int part[1024];
  int tid = threadIdx.x;
  int base = tid*32;
  int loc[32]; int s = 0;
#pragma unroll
  for(int i=0;i<32;i++){ loc[i] = s; s += cnt[base+i]; }
  part[tid] = s; __syncthreads();
  for(int d=1; d<1024; d<<=1){
    int v = (tid>=d) ? part[tid-d] : 0;
    __syncthreads();
    part[tid] += v;
    __syncthreads();
  }
  int pre = (tid==0) ? 0 : part[tid-1];
#pragma unroll
  for(int i=0;i<32;i++) off[base+i] = pre + loc[i];
  if(tid == 1023) off[NT] = part[1023];
}
__global__ void k_copyi(const int* __restrict__ a, int* __restrict__ b, int n){
  int i = blockIdx.x*256 + threadIdx.x;
  if(i < n) b[i] = a[i];
}
__global__ void k_fill(const int* __restrict__ ei, int* __restrict__ cur, int* __restrict__ csr){
  int id = blockIdx.x*256 + threadIdx.x;
  if(id >= EALL) return;
  int t = id >> 14, e = id & (E_-1);
  int d = ei[t*2*E_ + E_ + e];
  int pos = atomicAdd(&cur[t*N_ + d], 1);
  csr[pos] = id;                      // global edge id: t*E + e
}

// dinv[node] = 1/sqrt(1 + sum ew over incoming edges)
__global__ void k_degg(const float* __restrict__ ew, const int* __restrict__ off,
                       const int* __restrict__ csr, float* __restrict__ dinv){
  int n = blockIdx.x*256 + threadIdx.x;
  if(n >= NT) return;
  float s = 1.0f;
  for(int k=off[n]; k<off[n+1]; k++) s += ew[csr[k]];
  dinv[n] = rsqrtf(s);
}

// ---------------- MFMA GEMM: C[M,N] = act(A[M,K]) @ B[N,K]^T (+bias)(+relu) -------------
template<int TM,int TN,bool PREACT,bool EBIAS,bool ERELU,bool OBF16>
__global__ __launch_bounds__(256) void gemm_bt(
    const float* __restrict__ A, const float* __restrict__ ab,
    const float* __restrict__ B, const float* __restrict__ bias,
    float* __restrict__ Cf, short* __restrict__ Cb, int K, int N)
{
  const int lane = threadIdx.x & 63;
  const int wv   = threadIdx.x >> 6;
  const int wi = wv >> 1, wj = wv & 1;
  const int q = lane >> 4, r = lane & 15;
  const int m0 = blockIdx.y * (2*TM*16) + wi * (TM*16);
  const int n0 = blockIdx.x * (2*TN*16) + wj * (TN*16);

  f32x4 acc[TM][TN];
#pragma unroll
  for(int i=0;i<TM;i++)
#pragma unroll
    for(int j=0;j<TN;j++) acc[i][j] = (f32x4){0.f,0.f,0.f,0.f};

  for(int k0=0;k0<K;k0+=32){
    const int ka = k0 + q*8;
    short8 af[TM], bfr[TN];
#pragma unroll
    for(int i=0;i<TM;i++){
      const float* p = A + (size_t)(m0 + i*16 + r)*K + ka;
      float4 u0 = *(const float4*)p;
      float4 u1 = *(const float4*)(p+4);
      float vv[8] = {u0.x,u0.y,u0.z,u0.w,u1.x,u1.y,u1.z,u1.w};
      if (PREACT){
        const float* bb = ab + ka;
        float4 b0 = *(const float4*)bb;
        float4 b1 = *(const float4*)(bb+4);
        float bv[8] = {b0.x,b0.y,b0.z,b0.w,b1.x,b1.y,b1.z,b1.w};
#pragma unroll
        for(int u=0;u<8;u++) vv[u] = fmaxf(vv[u]+bv[u], 0.f);
      }
      short8 s;
#pragma unroll
      for(int u=0;u<8;u++) s[u] = f2bf(vv[u]);
      af[i] = s;
    }
#pragma unroll
    for(int j=0;j<TN;j++){
      const float* p = B + (size_t)(n0 + j*16 + r)*K + ka;
      float4 u0 = *(const float4*)p;
      float4 u1 = *(const float4*)(p+4);
      float vv[8] = {u0.x,u0.y,u0.z,u0.w,u1.x,u1.y,u1.z,u1.w};
      short8 s;
#pragma unroll
      for(int u=0;u<8;u++) s[u] = f2bf(vv[u]);
      bfr[j] = s;
    }
#pragma unroll
    for(int i=0;i<TM;i++)
#pragma unroll
      for(int j=0;j<TN;j++)
        acc[i][j] = __builtin_amdgcn_mfma_f32_16x16x32_bf16(af[i], bfr[j], acc[i][j], 0,0,0);
  }

#pragma unroll
  for(int i=0;i<TM;i++){
#pragma unroll
    for(int j=0;j<TN;j++){
#pragma unroll
      for(int rr=0;rr<4;rr++){
        int row = m0 + i*16 + q*4 + rr;
        int col = n0 + j*16 + r;
        float v = acc[i][j][rr];
        if(EBIAS) v += bias[col];
        if(ERELU) v = fmaxf(v, 0.f);
        if(OBF16) Cb[(size_t)row*N + col] = f2bf(v);
        else      Cf[(size_t)row*N + col] = v;
      }
    }
  }
}

// ---------------- Hop final GEMM: out[t] = h2bf[t] @ fcsum^T + fcb ; 128x128 tiles ------
__global__ __launch_bounds__(256) void hop_gemm(
    const short* __restrict__ Abf, const short* __restrict__ Bbf,
    const float* __restrict__ bias, float* __restrict__ out)
{
  const int lane = threadIdx.x & 63;
  const int wv   = threadIdx.x >> 6;
  const int wi = wv >> 1, wj = wv & 1;
  const int q = lane >> 4, r = lane & 15;
  const int t  = blockIdx.z;
  const int m0 = blockIdx.y * 128 + wi * 64;
  const int n0 = blockIdx.x * 128 + wj * 64;
  const short* Ab = Abf + (size_t)t * N_ * 128;

  f32x4 acc[4][4];
#pragma unroll
  for(int i=0;i<4;i++)
#pragma unroll
    for(int j=0;j<4;j++) acc[i][j] = (f32x4){0.f,0.f,0.f,0.f};

#pragma unroll
  for(int k0=0;k0<128;k0+=32){
    const int ka = k0 + q*8;
    short8 af[4], bfr[4];
#pragma unroll
    for(int i=0;i<4;i++) af[i]  = *(const short8*)(Ab  + (size_t)(m0 + i*16 + r)*128 + ka);
#pragma unroll
    for(int j=0;j<4;j++) bfr[j] = *(const short8*)(Bbf + (size_t)(n0 + j*16 + r)*128 + ka);
#pragma unroll
    for(int i=0;i<4;i++)
#pragma unroll
      for(int j=0;j<4;j++)
        acc[i][j] = __builtin_amdgcn_mfma_f32_16x16x32_bf16(af[i], bfr[j], acc[i][j], 0,0,0);
  }

#pragma unroll
  for(int i=0;i<4;i++){
#pragma unroll
    for(int j=0;j<4;j++){
#pragma unroll
      for(int rr=0;rr<4;rr++){
        int row = m0 + i*16 + q*4 + rr;
        int col = n0 + j*16 + r;
        out[((size_t)t*N_ + row)*N_ + col] = acc[i][j][rr] + bias[col];
      }
    }
  }
}

// ---------------- GAT layer 1 (H=4, C=128) ----------------------------------------------
// Attention state only matters for nodes < 2048 (edge ids stay < N); rows >= 2048
// have alpha_self = p/(p+1e-16) ~= 1 -> plain copy.
__global__ void k_asad1(const float* __restrict__ xw1, const float* __restrict__ atts,
                        const float* __restrict__ attd, float* __restrict__ as1,
                        float* __restrict__ ad1){
  int id = blockIdx.x*256 + threadIdx.x;     // N_ * 4
  if(id >= N_*4) return;
  int n = id >> 2, h = id & 3;
  const float* row = xw1 + (size_t)n*512 + h*128;
  const float* sa = atts + h*128;
  const float* da = attd + h*128;
  float s = 0.f, d = 0.f;
  for(int c=0;c<128;c+=4){
    float4 v = *(const float4*)(row+c);
    float4 a = *(const float4*)(sa+c);
    float4 b = *(const float4*)(da+c);
    s += v.x*a.x + v.y*a.y + v.z*a.z + v.w*a.w;
    d += v.x*b.x + v.y*b.y + v.z*b.z + v.w*b.w;
  }
  as1[id] = s; ad1[id] = d;
}

// per-dst gather: p1 stash + denominators (includes self term), d < 2048
__global__ __launch_bounds__(64) void k_den1g(
    const int* __restrict__ ei, const int* __restrict__ off, const int* __restrict__ csr,
    const float* __restrict__ as1, const float* __restrict__ ad1,
    float* __restrict__ p1, float* __restrict__ den1){
  int d = blockIdx.x;
  int lane = threadIdx.x;
  float ad[4];
#pragma unroll
  for(int h=0;h<4;h++) ad[h] = ad1[d*4+h];
  float sum[4] = {0.f,0.f,0.f,0.f};
  for(int t=0;t<16;t++){
    int key = t*N_ + d;
    int beg = off[key], end = off[key+1];
    for(int k=beg+lane; k<end; k+=64){
      int eid = csr[k];
      int e = eid & (E_-1);
      int s = ei[t*2*E_ + e];
#pragma unroll
      for(int h=0;h<4;h++){
        float p = expf(lrelu(as1[s*4+h] + ad[h]));
        p1[(size_t)eid*4+h] = p;
        sum[h] += p;
      }
    }
  }
#pragma unroll
  for(int h=0;h<4;h++)
    for(int o=32;o;o>>=1) sum[h] += __shfl_down(sum[h], o);
  if(lane == 0){
#pragma unroll
    for(int h=0;h<4;h++)
      den1[d*4+h] = sum[h] + expf(lrelu(as1[d*4+h] + ad[h]));
  }
}

// rows >= 2048: z1 = xw1 (alpha_self ~= 1)
__global__ void k_z1copy(const float* __restrict__ xw1, float* __restrict__ z1){
  int id = blockIdx.x*256 + threadIdx.x;     // (NT-N_)*128 float4 chunks
  if(id >= (NT-N_)*128) return;
  size_t o = (size_t)N_*512 + (size_t)id*4;
  *(float4*)(z1 + o) = *(const float4*)(xw1 + o);
}

// rows < 2048: gather over incoming edges (all t) + self
__global__ __launch_bounds__(256) void k_z1g(
    const int* __restrict__ ei, const int* __restrict__ off, const int* __restrict__ csr,
    const float* __restrict__ p1, const float* __restrict__ den1,
    const float* __restrict__ as1, const float* __restrict__ ad1,
    const float* __restrict__ xw1, float* __restrict__ z1){
  int d = blockIdx.x;
  int tid = threadIdx.x;
  int h = tid >> 6;                          // 2 channels per thread
  float deninv = 1.f/(den1[d*4+h] + 1e-16f);
  float aself = expf(lrelu(as1[d*4+h] + ad1[d*4+h])) * deninv;
  float2 v = *(const float2*)(xw1 + (size_t)d*512 + tid*2);
  float accx = v.x*aself, accy = v.y*aself;
  for(int t=0;t<16;t++){
    int key = t*N_ + d;
    int beg = off[key], end = off[key+1];
    for(int k=beg; k<end; k++){
      int eid = csr[k];
      int e = eid & (E_-1);
      int s = ei[t*2*E_ + e];
      float w = p1[(size_t)eid*4+h] * deninv;
      float2 u = *(const float2*)(xw1 + (size_t)s*512 + tid*2);
      accx += u.x*w; accy += u.y*w;
    }
  }
  float2 o; o.x = accx; o.y = accy;
  *(float2*)(z1 + (size_t)d*512 + tid*2) = o;
}

// ---------------- GAT layer 2 (H=1, C=64) -----------------------------------------------
__global__ void k_asad2(const float* __restrict__ xw2, const float* __restrict__ atts,
                        const float* __restrict__ attd, float* __restrict__ as2,
                        float* __restrict__ ad2){
  int n = blockIdx.x*256 + threadIdx.x;
  if(n >= N_) return;
  const float* row = xw2 + (size_t)n*64;
  float s = 0.f, d = 0.f;
  for(int c=0;c<64;c+=4){
    float4 v = *(const float4*)(row+c);
    float4 a = *(const float4*)(atts+c);
    float4 b = *(const float4*)(attd+c);
    s += v.x*a.x + v.y*a.y + v.z*a.z + v.w*a.w;
    d += v.x*b.x + v.y*b.y + v.z*b.z + v.w*b.w;
  }
  as2[n] = s; ad2[n] = d;
}

__global__ __launch_bounds__(64) void k_den2g(
    const int* __restrict__ ei, const int* __restrict__ off, const int* __restrict__ csr,
    const float* __restrict__ as2, const float* __restrict__ ad2,
    float* __restrict__ p2, float* __restrict__ den2){
  int d = blockIdx.x;
  int lane = threadIdx.x;
  float ad = ad2[d];
  float sum = 0.f;
  for(int t=0;t<16;t++){
    int key = t*N_ + d;
    int beg = off[key], end = off[key+1];
    for(int k=beg+lane; k<end; k+=64){
      int eid = csr[k];
      int e = eid & (E_-1);
      int s = ei[t*2*E_ + e];
      float p = expf(lrelu(as2[s] + ad));
      p2[eid] = p;
      sum += p;
    }
  }
  for(int o=32;o;o>>=1) sum += __shfl_down(sum, o);
  if(lane == 0) den2[d] = sum + expf(lrelu(as2[d] + ad));
}

__global__ void k_z2copy(const float* __restrict__ xw2, const float* __restrict__ b2,
                         float* __restrict__ z2){
  int id = blockIdx.x*256 + threadIdx.x;     // (NT-N_)*16 float4 chunks
  if(id >= (NT-N_)*16) return;
  int c4 = id & 15;
  size_t o = (size_t)N_*64 + (size_t)id*4;
  float4 v = *(const float4*)(xw2 + o);
  float4 b = *(const float4*)(b2 + c4*4);
  float4 w; w.x=v.x+b.x; w.y=v.y+b.y; w.z=v.z+b.z; w.w=v.w+b.w;
  *(float4*)(z2 + o) = w;
}

__global__ __launch_bounds__(64) void k_z2g(
    const int* __restrict__ ei, const int* __restrict__ off, const int* __restrict__ csr,
    const float* __restrict__ p2, const float* __restrict__ den2,
    const float* __restrict__ as2, const float* __restrict__ ad2,
    const float* __restrict__ xw2, const float* __restrict__ b2, float* __restrict__ z2){
  int d = blockIdx.x;
  int ch = threadIdx.x;
  float deninv = 1.f/(den2[d] + 1e-16f);
  float aself = expf(lrelu(as2[d] + ad2[d])) * deninv;
  float acc = xw2[(size_t)d*64 + ch]*aself + b2[ch];
  for(int t=0;t<16;t++){
    int key = t*N_ + d;
    int beg = off[key], end = off[key+1];
    for(int k=beg; k<end; k++){
      int eid = csr[k];
      int e = eid & (E_-1);
      int s = ei[t*2*E_ + e];
      float w = p2[eid] * deninv;
      acc += xw2[(size_t)s*64 + ch]*w;
    }
  }
  z2[(size_t)d*64 + ch] = acc;
}

__global__ void k_linkpred(const float* __restrict__ z2, const int* __restrict__ eli,
                           float* __restrict__ out){
  int pair = blockIdx.x*4 + (threadIdx.x >> 6);
  int lane = threadIdx.x & 63;
  if(pair >= EL_) return;
  int a = eli[pair], b = eli[EL_ + pair];
  float v = z2[(size_t)a*64 + lane] * z2[(size_t)b*64 + lane];
  for(int off=32; off; off >>= 1) v += __shfl_down(v, off);
  if(lane == 0) out[pair] = v;
}

// ---------------- GCN gather: out[node] = self + sum coeff*feats[src] -------------------
template<int F>
__global__ __launch_bounds__(F) void k_gcng(
    const int* __restrict__ ei, const float* __restrict__ ew,
    const float* __restrict__ dinv, const float* __restrict__ feats,
    const int* __restrict__ off, const int* __restrict__ csr, float* __restrict__ out){
  int node = blockIdx.x;
  int ch = threadIdx.x;
  int t = node >> 11;
  float di = dinv[node];
  float acc = di*di*feats[(size_t)node*F + ch];
  int beg = off[node], end = off[node+1];
  for(int k=beg; k<end; k++){
    int eid = csr[k];
    int e = eid & (E_-1);
    int s = ei[t*2*E_ + e];
    int gs = t*N_ + s;
    float coeff = dinv[gs]*ew[eid]*di;
    acc += coeff*feats[(size_t)gs*F + ch];
  }
  out[(size_t)node*F + ch] = acc;
}

__global__ void k_fcsum(const float* __restrict__ fcw, short* __restrict__ wbf){
  int id = blockIdx.x*256 + threadIdx.x;     // 2048*128
  if(id >= N_*128) return;
  int j = id >> 7, k = id & 127;
  wbf[id] = f2bf(fcw[j*256 + k] + fcw[j*256 + 128 + k]);
}

// ---------------- launcher --------------------------------------------------------------
extern "C" void kernel_launch(void* const* d_in, const int* in_sizes, int n_in,
                              void* d_out, int out_size, void* d_ws, size_t ws_size,
                              hipStream_t stream) {
  const float* x       = (const float*)d_in[0];
  const int*   ei      = (const int*)d_in[1];
  const float* eattr   = (const float*)d_in[2];
  const int*   eli     = (const int*)d_in[3];
  const float* conv1_w = (const float*)d_in[4];
  const float* conv1_b = (const float*)d_in[5];
  const float* conv2_w = (const float*)d_in[6];
  const float* conv2_b = (const float*)d_in[7];
  const float* gat1_w  = (const float*)d_in[8];
  const float* g1as    = (const float*)d_in[9];
  const float* g1ad    = (const float*)d_in[10];
  const float* gat1_b  = (const float*)d_in[11];
  const float* gat2_w  = (const float*)d_in[12];
  const float* g2as    = (const float*)d_in[13];
  const float* g2ad    = (const float*)d_in[14];
  const float* gat2_b  = (const float*)d_in[15];
  const float* fcw     = (const float*)d_in[16];
  const float* fcb     = (const float*)d_in[17];

  // workspace carve
  char* wp = (char*)d_ws;
  auto alloc = [&](size_t bytes)->void*{ void* r = wp; wp += (bytes + 255) & ~(size_t)255; return r; };
  int*   cnt   = (int*)alloc((size_t)NT*4);
  int*   off   = (int*)alloc((size_t)(NT+1)*4);
  int*   cur   = (int*)alloc((size_t)NT*4);
  int*   csr   = (int*)alloc((size_t)EALL*4);
  float* as1   = (float*)alloc((size_t)N_*4*4);
  float* ad1   = (float*)alloc((size_t)N_*4*4);
  float* den1  = (float*)alloc((size_t)N_*4*4);
  float* p1    = (float*)alloc((size_t)EALL*4*4);
  float* xw2   = (float*)alloc((size_t)NT*64*4);
  float* as2   = (float*)alloc((size_t)N_*4);
  float* ad2   = (float*)alloc((size_t)N_*4);
  float* den2  = (float*)alloc((size_t)N_*4);
  float* p2    = (float*)alloc((size_t)EALL*4);
  float* z2    = (float*)alloc((size_t)NT*64*4);
  float* dinv  = (float*)alloc((size_t)NT*4);
  float* accx  = (float*)alloc((size_t)NT*64*4);
  float* h1    = (float*)alloc((size_t)NT*128*4);
  float* acch  = (float*)alloc((size_t)NT*128*4);
  short* h2bf  = (short*)alloc((size_t)NT*128*2);
  short* fcsbf = (short*)alloc((size_t)N_*128*2);

  // d_out layout: [0:8192) link_pred, [8192:...) hop_out (16*2048*2048).
  // Hop region doubles as scratch for the two 64MB GAT buffers (consumed
  // before hop_gemm overwrites the region).
  float* outf     = (float*)d_out;
  float* link_out = outf;
  float* hop_out  = outf + EL_;
  float* xw1      = hop_out;                       // 16,777,216 floats
  float* z1       = hop_out + (size_t)NT*512;      // 16,777,216 floats

  dim3 blk(256);

  // ---- CSR build ----
  k_zero<<<dim3(NT/256), blk, 0, stream>>>(cnt, NT);
  k_cnt<<<dim3(EALL/256), blk, 0, stream>>>(ei, cnt);
  k_scan<<<dim3(1), dim3(1024), 0, stream>>>(cnt, off);
  k_copyi<<<dim3(NT/256), blk, 0, stream>>>(off, cur, NT);
  k_fill<<<dim3(EALL/256), blk, 0, stream>>>(ei, cur, csr);
  k_degg<<<dim3(NT/256), blk, 0, stream>>>(eattr, off, csr, dinv);

  // ---- GAT branch ----
  gemm_bt<4,4,false,false,false,false><<<dim3(4,256), blk, 0, stream>>>(
      x, nullptr, gat1_w, nullptr, xw1, nullptr, 64, 512);
  k_asad1<<<dim3((N_*4)/256), blk, 0, stream>>>(xw1, g1as, g1ad, as1, ad1);
  k_den1g<<<dim3(N_), dim3(64), 0, stream>>>(ei, off, csr, as1, ad1, p1, den1);
  k_z1copy<<<dim3(((NT-N_)*128)/256), blk, 0, stream>>>(xw1, z1);
  k_z1g<<<dim3(N_), blk, 0, stream>>>(ei, off, csr, p1, den1, as1, ad1, xw1, z1);
  gemm_bt<4,2,true,false,false,false><<<dim3(1,256), blk, 0, stream>>>(
      z1, gat1_b, gat2_w, nullptr, xw2, nullptr, 512, 64);
  k_asad2<<<dim3(N_/256), blk, 0, stream>>>(xw2, g2as, g2ad, as2, ad2);
  k_den2g<<<dim3(N_), dim3(64), 0, stream>>>(ei, off, csr, as2, ad2, p2, den2);
  k_z2copy<<<dim3(((NT-N_)*16)/256), blk, 0, stream>>>(xw2, gat2_b, z2);
  k_z2g<<<dim3(N_), dim3(64), 0, stream>>>(ei, off, csr, p2, den2, as2, ad2, xw2, gat2_b, z2);
  k_linkpred<<<dim3(EL_/4), blk, 0, stream>>>(z2, eli, link_out);

  // ---- hop (GCN) branch ----
  k_gcng<64><<<dim3(NT), dim3(64), 0, stream>>>(ei, eattr, dinv, x, off, csr, accx);
  gemm_bt<4,4,false,true,true,false><<<dim3(1,256), blk, 0, stream>>>(
      accx, nullptr, conv1_w, conv1_b, h1, nullptr, 64, 128);
  k_gcng<128><<<dim3(NT), dim3(128), 0, stream>>>(ei, eattr, dinv, h1, off, csr, acch);
  gemm_bt<4,4,false,true,true,true><<<dim3(1,256), blk, 0, stream>>>(
      acch, nullptr, conv2_w, conv2_b, nullptr, h2bf, 128, 128);
  k_fcsum<<<dim3((N_*128)/256), blk, 0, stream>>>(fcw, fcsbf);
  hop_gemm<<<dim3(16,16,16), blk, 0, stream>>>(h2bf, fcsbf, fcb, hop_out);
}